// Round 10
// baseline (449.118 us; speedup 1.0000x reference)
//
#include <hip/hip_runtime.h>

// MessagePassingConvolution, round 20.
// Revert to the PROVEN best pipeline (R5/v15 sorted, 286.4us total:
// build 97 + node 94.5 + hist ~25 + scan + gaps) with two surgical cuts:
//  1. scan: wave-shuffle scan (2 block barriers instead of 30). Same
//     1-block shape (parallel 3-kernel split cost more in gaps, R7).
//  2. node: v19's verified 2xfdot2+const edge-factor (was 3 fdot2) via
//     record pack qb = {e0|e1x, e1y|e1z, snd, 0}. Record stays 32 B and
//     snd stays INSIDE the record line (R9 lesson: a separate senders[]
//     gather costs a full 64-B line per edge, +106MB FETCH).
// Unsorted CAP-bucket branch retired: 3 rounds (R6/R8/R9) never beat
// sorted; ws proven only >= 51.8MB which can't hold recs+bucket.
//
// Record (32 B): uint4 A = h[0..7] as 4x half2 ;
//                uint4 B = {e0|e1x, e1y|e1z, snd, 0}.
// h = swish(r@w1)/sqrt(32); 1/sqrt(3) folded into per-lane w2 col.
//
// product table (112 products -> out[96]):
//  slot0 (64 lanes):
//   lanes  0..7 : out[c]=lane      k=lane    i=lane    f=1        (s*w)
//   lanes  8..15: out[c]=lane      k=lane    i=lane-8  f=e0       (s*e0*w)
//   lanes 16..39: t=lane-16, m=t/3, x=t%3 -> partial of out[16+m]:
//                 k=16+m (w*1/sqrt3) i=8+t   f=e1[x]   (dot(v,e1) terms)
//   lanes 40..63: t=lane-40 -> out[24+t]    k=24+t/3 i=8+t f=1    (v*w)
//  slot1 (48 lanes used):
//   lanes  0..23: t=lane, m=t/3, x=t%3 -> out[48+t] k=32+m i=m f=e1[x]
//   lanes 24..47: t=lane-24 -> out[72+t]   k=40+t/3 i=8+t   f=e0
//   lanes 48..63: dead (w cols zeroed)

#define CH 16   // records staged per chunk in node kernel

typedef _Float16 half2v __attribute__((ext_vector_type(2)));

__device__ __forceinline__ unsigned pk16(float a, float b) {
    return __builtin_bit_cast(unsigned, __builtin_amdgcn_cvt_pkrtz(a, b));
}

__device__ __forceinline__ float dot2h(unsigned a, half2v b, float c) {
#if __has_builtin(__builtin_amdgcn_fdot2)
    return __builtin_amdgcn_fdot2(__builtin_bit_cast(half2v, a), b, c, false);
#else
    half2v av = __builtin_bit_cast(half2v, a);
    return fmaf((float)av.x, (float)b.x, fmaf((float)av.y, (float)b.y, c));
#endif
}

__global__ __launch_bounds__(256) void hist_kernel(
    const int* __restrict__ recv, int* __restrict__ cnt, int E)
{
    int e = blockIdx.x * 256 + threadIdx.x;
    if (e < E) atomicAdd(&cnt[recv[e]], 1);
}

// 1-block scan, wave-shuffle based: 2 barriers total (was 30).
__global__ __launch_bounds__(1024) void scan_kernel(
    const int* __restrict__ cnt, int* __restrict__ off,
    int* __restrict__ cursor, int N, int E)
{
    __shared__ int wsum[16];
    const int t = threadIdx.x;
    const int lane = t & 63;
    const int wid = t >> 6;
    const int CHN = (N + 1023) / 1024;
    const int lo = t * CHN;
    const int hi = min(N, lo + CHN);
    int s = 0;
    for (int i = lo; i < hi; ++i) s += cnt[i];

    // wave-inclusive scan of per-thread chunk sums (no barriers)
    int v = s;
#pragma unroll
    for (int d = 1; d < 64; d <<= 1) {
        int u = __shfl(v, lane - d);
        if (lane >= d) v += u;
    }
    if (lane == 63) wsum[wid] = v;
    __syncthreads();
    if (wid == 0) {
        int w = (lane < 16) ? wsum[lane] : 0;
#pragma unroll
        for (int d = 1; d < 16; d <<= 1) {
            int u = __shfl(w, lane - d);
            if (lane >= d) w += u;
        }
        if (lane < 16) wsum[lane] = w;   // inclusive wave totals
    }
    __syncthreads();
    const int wbase = (wid > 0) ? wsum[wid - 1] : 0;

    int run = wbase + v - s;   // exclusive prefix of this thread's chunk
    for (int i = lo; i < hi; ++i) {
        off[i] = run;
        cursor[i] = run;
        run += cnt[i];
    }
    if (t == 1023) off[N] = E;
}

// Edge-parallel: radial MLP, pack 32-B f16 record at sorted slot.
__global__ __launch_bounds__(256) void build_recs_kernel(
    const float* __restrict__ edge_features, // E x 4
    const float* __restrict__ radial,        // E x 8
    const float* __restrict__ w1g,           // 8 x 8
    const int* __restrict__ senders,
    const int* __restrict__ recv,
    int* __restrict__ cursor,
    uint4* __restrict__ recs,                // 2 x uint4 per record
    int E)
{
    __shared__ float sw1[64];
    for (int i = threadIdx.x; i < 64; i += 256) sw1[i] = w1g[i];
    __syncthreads();

    int e = blockIdx.x * 256 + threadIdx.x;
    if (e >= E) return;

    const int rcv_ = recv[e];
    // atomic first: overlap its latency with the MLP
    const size_t addr = (size_t)atomicAdd(&cursor[rcv_], 1);

    const float4 ef = reinterpret_cast<const float4*>(edge_features)[e];
    const float4 ra = reinterpret_cast<const float4*>(radial)[2 * e + 0];
    const float4 rb = reinterpret_cast<const float4*>(radial)[2 * e + 1];
    const int snd = senders[e];

    float r[8] = {ra.x, ra.y, ra.z, ra.w, rb.x, rb.y, rb.z, rb.w};
    float h[8];
#pragma unroll
    for (int j = 0; j < 8; ++j) {
        float x = 0.f;
#pragma unroll
        for (int i = 0; i < 8; ++i) x = fmaf(r[i], sw1[i * 8 + j], x);
        // swish with 1/sqrt(32) folded
        h[j] = 0.17677669529663687f * x * __builtin_amdgcn_rcpf(1.0f + __expf(-x));
    }

    uint4 qa, qb;
    qa.x = pk16(h[0], h[1]); qa.y = pk16(h[2], h[3]);
    qa.z = pk16(h[4], h[5]); qa.w = pk16(h[6], h[7]);
    qb.x = pk16(ef.x, ef.y);     // (e0, e1x)
    qb.y = pk16(ef.z, ef.w);     // (e1y, e1z)
    qb.z = (unsigned)snd;
    qb.w = 0u;
    recs[2 * addr + 0] = qa;
    recs[2 * addr + 1] = qb;
}

// One wave per node, 4 nodes/block, no barriers (wave-private LDS regions).
// v15/v17 proven structure: contiguous records, wave-uniform scalar loads.
__global__ __launch_bounds__(256) void node_v20_kernel(
    const float* __restrict__ node_feats,    // N x 32
    const float* __restrict__ w2g,           // 8 x 48
    const int* __restrict__ off,             // off[N+1]
    const uint4* __restrict__ recs,
    float* __restrict__ out,                 // N x 96
    int N)
{
    const int lane = threadIdx.x & 63;
    const int wv   = threadIdx.x >> 6;   // 0..3 = local node
    const int node = blockIdx.x * 4 + wv;

    __shared__ float nf_lds[4][CH][36];      // 9 KB (36: bank-balanced writes)
    __shared__ float scr[4][128];            // 2 KB epilogue scratch

    // ---- per-lane product-slot tables (all loop-invariant) ----
    int kA, iA, selA; float scA = 1.0f;
    if (lane < 8)       { kA = lane;         iA = lane;     selA = 0; }
    else if (lane < 16) { kA = lane;         iA = lane - 8; selA = 1; }
    else if (lane < 40) { int t = lane - 16; kA = 16 + t / 3; iA = 8 + t;
                          selA = 2 + t % 3;  scA = 0.57735026918962576f; }
    else                { int t = lane - 40; kA = 24 + t / 3; iA = 8 + t; selA = 0; }

    int kB, iB, selB; const bool deadB = (lane >= 48);
    if (lane < 24)      { int t = lane;      kB = 32 + t / 3; iB = t / 3; selB = 2 + t % 3; }
    else if (lane < 48) { int t = lane - 24; kB = 40 + t / 3; iB = 8 + t; selB = 1; }
    else                { kB = 0; iB = 0; selB = 0; }

    // edge-factor = dot2(qb.x=(e0,e1x), m0) + dot2(qb.y=(e1y,e1z), m1) + c
    // sel: 0 -> c=1 ; 1 -> m0.x ; 2 -> m0.y ; 3 -> m1.x ; 4 -> m1.y
    // (mask scheme verbatim from v19's node, which passed correctness)
    half2v mA0 = {0, 0}, mA1 = {0, 0};
    float cA = 0.f;
    if      (selA == 0) cA = 1.f;
    else if (selA == 1) mA0.x = (_Float16)1.f;
    else if (selA == 2) mA0.y = (_Float16)1.f;
    else if (selA == 3) mA1.x = (_Float16)1.f;
    else                mA1.y = (_Float16)1.f;
    half2v mB0 = {0, 0}, mB1 = {0, 0};
    if (!deadB) {
        if      (selB == 1) mB0.x = (_Float16)1.f;
        else if (selB == 2) mB0.y = (_Float16)1.f;
        else if (selB == 3) mB1.x = (_Float16)1.f;
        else                mB1.y = (_Float16)1.f;
    }

    half2v wpA[4], wpB[4];
#pragma unroll
    for (int i = 0; i < 4; ++i) {
        wpA[i].x = (_Float16)(w2g[(2 * i + 0) * 48 + kA] * scA);
        wpA[i].y = (_Float16)(w2g[(2 * i + 1) * 48 + kA] * scA);
        wpB[i].x = deadB ? (_Float16)0.f : (_Float16)(w2g[(2 * i + 0) * 48 + kB]);
        wpB[i].y = deadB ? (_Float16)0.f : (_Float16)(w2g[(2 * i + 1) * 48 + kB]);
    }

    if (node >= N) return;  // safe: no __syncthreads in this kernel

    int base  = off[node];
    int count = off[node + 1] - base;
    // scalar-root: wave-uniform values into SGPRs so record reads become
    // s_load through the scalar cache (off the LDS/VALU pipes entirely)
    base  = __builtin_amdgcn_readfirstlane(base);
    count = __builtin_amdgcn_readfirstlane(count);
    const uint4* rp = recs + (size_t)base * 2;

    const int r_stage = lane >> 2;       // 0..15: which record's nf row I stage
    const int q_stage = lane & 3;        // 0..3: which quarter of the row

    float acc0 = 0.f, acc1 = 0.f;

    for (int c0i = 0; c0i < count; c0i += CH) {
        const int cc = min(CH, count - c0i);

        // ---- stage sender nf rows: 4 lanes per record ----
        // snd read from GLOBAL recs (dword 6 of the record line)
        if (r_stage < cc) {
            const unsigned snd =
                reinterpret_cast<const unsigned*>(rp)[((size_t)c0i + r_stage) * 8 + 6];
            const float4* src = reinterpret_cast<const float4*>(node_feats)
                                + (size_t)snd * 8 + q_stage * 2;
            const float4 v0 = src[0];
            const float4 v1 = src[1];
            float* dst = &nf_lds[wv][r_stage][q_stage * 8];
            *reinterpret_cast<float4*>(dst)     = v0;
            *reinterpret_cast<float4*>(dst + 4) = v1;
        }

        // ---- compute: records via scalar loads, nf via LDS b32 ----
#pragma unroll 4
        for (int i = 0; i < cc; ++i) {
            const uint4 qa = rp[(size_t)(c0i + i) * 2 + 0];  // uniform -> s_load
            const uint4 qb = rp[(size_t)(c0i + i) * 2 + 1];  // uniform -> s_load

            float wAv = dot2h(qa.x, wpA[0], 0.f);
            wAv = dot2h(qa.y, wpA[1], wAv);
            wAv = dot2h(qa.z, wpA[2], wAv);
            wAv = dot2h(qa.w, wpA[3], wAv);
            float wBv = dot2h(qa.x, wpB[0], 0.f);
            wBv = dot2h(qa.y, wpB[1], wBv);
            wBv = dot2h(qa.z, wpB[2], wBv);
            wBv = dot2h(qa.w, wpB[3], wBv);

            // edge factor: 2 fdot2 + folded constant (v19 scheme)
            const float fA = dot2h(qb.x, mA0, dot2h(qb.y, mA1, cA));
            const float fB = dot2h(qb.x, mB0, dot2h(qb.y, mB1, 0.f));

            const float n0 = nf_lds[wv][i][iA];   // conflict-free
            const float n1 = nf_lds[wv][i][iB];   // broadcast groups

            acc0 = fmaf(wAv, n0 * fA, acc0);
            acc1 = fmaf(wBv, n1 * fB, acc1);
        }
    }

    // ---- epilogue: merge type2 triples, permute to output layout ----
    scr[wv][lane]      = acc0;
    scr[wv][64 + lane] = acc1;
    // same-wave LDS: no barrier needed, compiler inserts lgkmcnt waits
    float o0;
    if (lane < 16) {
        o0 = scr[wv][lane];
    } else if (lane < 24) {
        const int t = 16 + 3 * (lane - 16);
        o0 = scr[wv][t] + scr[wv][t + 1] + scr[wv][t + 2];
    } else {
        o0 = scr[wv][lane + 16];   // comps 24..47 <- slot0[40+..]; 48..63 <- slot1[0..15]
    }
    float* orow = out + (size_t)node * 96;
    orow[lane] = o0;
    if (lane < 32) orow[64 + lane] = scr[wv][80 + lane];  // comps 64..95 <- slot1[16..47]
}

extern "C" void kernel_launch(void* const* d_in, const int* in_sizes, int n_in,
                              void* d_out, int out_size, void* d_ws, size_t ws_size,
                              hipStream_t stream) {
    const float* node_feats    = (const float*)d_in[0];
    const float* edge_features = (const float*)d_in[1];
    const float* radial        = (const float*)d_in[2];
    const float* w1            = (const float*)d_in[3];
    const float* w2            = (const float*)d_in[4];
    const int*   senders       = (const int*)d_in[5];
    const int*   receivers     = (const int*)d_in[6];
    float* out = (float*)d_out;

    const int E = in_sizes[5];
    const int N = out_size / 96;
    const int eblocks = (E + 255) / 256;
    const int nblocks = (N + 3) / 4;   // 4 nodes/block, 1 wave/node

    // ws layout: recs[E*32] | cnt[N] | off[N+1] | cursor[N]  (51.8 MB, proven)
    uint4* recs = (uint4*)d_ws;
    int* cnt    = (int*)((char*)d_ws + (size_t)E * 32);
    int* off    = cnt + N;
    int* cursor = off + N + 1;

    (void)hipMemsetAsync(cnt, 0, (size_t)N * sizeof(int), stream);
    hipLaunchKernelGGL(hist_kernel, dim3(eblocks), dim3(256), 0, stream,
                       receivers, cnt, E);
    hipLaunchKernelGGL(scan_kernel, dim3(1), dim3(1024), 0, stream,
                       cnt, off, cursor, N, E);
    hipLaunchKernelGGL(build_recs_kernel, dim3(eblocks), dim3(256), 0, stream,
                       edge_features, radial, w1, senders, receivers,
                       cursor, recs, E);
    hipLaunchKernelGGL(node_v20_kernel, dim3(nblocks), dim3(256), 0, stream,
                       node_feats, w2, off, recs, out, N);
}

// Round 11
// 363.529 us; speedup vs baseline: 1.2354x; 1.2354x over previous
//
#include <hip/hip_runtime.h>

// MessagePassingConvolution, round 21.
// R10 findings: the 1-block scan is ~110us SERIAL (0.14% occupancy, 0.01%
// VALU -- one CU chewing latency); shuffle micro-opt made it worse, the
// fix is parallelism. v21 = byte-proven R5/R7 pipeline (build <=97us,
// node 94.5us, hist ~25us, all measured) with ONE change:
//  - scan -> single-dispatch ticket-ordered CHAINED scan, 25 blocks x 2048
//    elems. Local LDS scan in parallel; thread0 spins on prev tile's
//    published inclusive prefix (one atomic int IS the message -- no
//    fencing needed) then publishes its own. Ticket order = block start
//    order -> predecessor always resident -> no deadlock (25 blocks << 256
//    CUs, workgroups never preempted). chain/tilecnt re-init rides inside
//    hist (stream-ordered), so graph replays are identical. 5 dispatches.
//
// Record (32 B): uint4 A = h[0..7] as 4x half2 ;
//                uint4 B = {1|e0, e1x|e1y, snd, e1z|0}.
// h = swish(r@w1)/sqrt(32); 1/sqrt(3) folded into per-lane w2 col.
//
// product table (112 products -> out[96]):
//  slot0 (64 lanes):
//   lanes  0..7 : out[c]=lane      k=lane    i=lane    f=1        (s*w)
//   lanes  8..15: out[c]=lane      k=lane    i=lane-8  f=e0       (s*e0*w)
//   lanes 16..39: t=lane-16, m=t/3, x=t%3 -> partial of out[16+m]:
//                 k=16+m (w*1/sqrt3) i=8+t   f=e1[x]   (dot(v,e1) terms)
//   lanes 40..63: t=lane-40 -> out[24+t]    k=24+t/3 i=8+t f=1    (v*w)
//  slot1 (48 lanes used):
//   lanes  0..23: t=lane, m=t/3, x=t%3 -> out[48+t] k=32+m i=m f=e1[x]
//   lanes 24..47: t=lane-24 -> out[72+t]   k=40+t/3 i=8+t   f=e0
//   lanes 48..63: dead (w cols zeroed)

#define CH 16   // records staged per chunk in node kernel

typedef _Float16 half2v __attribute__((ext_vector_type(2)));

__device__ __forceinline__ unsigned pk16(float a, float b) {
    return __builtin_bit_cast(unsigned, __builtin_amdgcn_cvt_pkrtz(a, b));
}

__device__ __forceinline__ float dot2h(unsigned a, half2v b, float c) {
#if __has_builtin(__builtin_amdgcn_fdot2)
    return __builtin_amdgcn_fdot2(__builtin_bit_cast(half2v, a), b, c, false);
#else
    half2v av = __builtin_bit_cast(half2v, a);
    return fmaf((float)av.x, (float)b.x, fmaf((float)av.y, (float)b.y, c));
#endif
}

// hist + re-init of the scan's chain/ticket state (stream-ordered before scan)
__global__ __launch_bounds__(256) void hist_kernel(
    const int* __restrict__ recv, int* __restrict__ cnt,
    int* __restrict__ chain, int* __restrict__ tilecnt, int E, int T)
{
    const int g = blockIdx.x * 256 + threadIdx.x;
    if (g < T) chain[g] = -1;      // sentinel: prefix not yet published
    if (g == T) *tilecnt = 0;      // ticket counter
    if (g < E) atomicAdd(&cnt[recv[g]], 1);
}

// Single-dispatch chained scan: 256 threads x 8 elems = 2048/tile.
__global__ __launch_bounds__(256) void scan_chain_kernel(
    const int* __restrict__ cnt, int* __restrict__ off,
    int* __restrict__ cursor, int* __restrict__ chain,
    int* __restrict__ tilecnt, int N, int E, int T)
{
    __shared__ int lds[256];
    __shared__ int sh_tile, sh_base;
    const int t = threadIdx.x;
    if (t == 0) sh_tile = atomicAdd(tilecnt, 1);   // ticket = start order
    __syncthreads();
    const int tile = sh_tile;
    const int i0 = tile * 2048 + t * 8;

    int v[8];
    int s = 0;
#pragma unroll
    for (int k = 0; k < 8; ++k) {
        const int i = i0 + k;
        v[k] = (i < N) ? cnt[i] : 0;
        s += v[k];
    }
    lds[t] = s;
    __syncthreads();
#pragma unroll
    for (int d = 1; d < 256; d <<= 1) {
        const int u = (t >= d) ? lds[t - d] : 0;
        __syncthreads();
        lds[t] += u;
        __syncthreads();
    }
    const int p = lds[t] - s;            // exclusive prefix within tile

    if (t == 0) {
        const int tot = lds[255];        // tile total
        int prev = 0;
        if (tile > 0) {
            // spin on predecessor's published inclusive prefix; the atomic
            // int carries the value itself -> no separate fence needed
            do { prev = atomicAdd(&chain[tile - 1], 0); } while (prev == -1);
        }
        sh_base = prev;
        atomicExch(&chain[tile], prev + tot);   // publish my inclusive prefix
    }
    __syncthreads();

    int run = sh_base + p;
#pragma unroll
    for (int k = 0; k < 8; ++k) {
        const int i = i0 + k;
        if (i < N) { off[i] = run; cursor[i] = run; }
        run += v[k];
    }
    if (tile == T - 1 && t == 255) off[N] = E;
}

// Edge-parallel: radial MLP, pack 32-B f16 record at sorted slot.
// Byte-equivalent to the R5/R7 proven build (<=97us measured).
__global__ __launch_bounds__(256) void build_recs_kernel(
    const float* __restrict__ edge_features, // E x 4
    const float* __restrict__ radial,        // E x 8
    const float* __restrict__ w1g,           // 8 x 8
    const int* __restrict__ senders,
    const int* __restrict__ recv,
    int* __restrict__ cursor,
    uint4* __restrict__ recs,                // 2 x uint4 per record
    int E)
{
    __shared__ float sw1[64];
    for (int i = threadIdx.x; i < 64; i += 256) sw1[i] = w1g[i];
    __syncthreads();

    int e = blockIdx.x * 256 + threadIdx.x;
    if (e >= E) return;

    const int rcv_ = recv[e];
    // atomic first: overlap its latency with the MLP
    const size_t addr = (size_t)atomicAdd(&cursor[rcv_], 1);

    const float4 ef = reinterpret_cast<const float4*>(edge_features)[e];
    const float4 ra = reinterpret_cast<const float4*>(radial)[2 * e + 0];
    const float4 rb = reinterpret_cast<const float4*>(radial)[2 * e + 1];
    const int snd = senders[e];

    float r[8] = {ra.x, ra.y, ra.z, ra.w, rb.x, rb.y, rb.z, rb.w};
    float h[8];
#pragma unroll
    for (int j = 0; j < 8; ++j) {
        float x = 0.f;
#pragma unroll
        for (int i = 0; i < 8; ++i) x = fmaf(r[i], sw1[i * 8 + j], x);
        // swish with 1/sqrt(32) folded
        h[j] = 0.17677669529663687f * x * __builtin_amdgcn_rcpf(1.0f + __expf(-x));
    }

    uint4 qa, qb;
    qa.x = pk16(h[0], h[1]); qa.y = pk16(h[2], h[3]);
    qa.z = pk16(h[4], h[5]); qa.w = pk16(h[6], h[7]);
    qb.x = pk16(1.0f, ef.x);     // (1, e0)
    qb.y = pk16(ef.y, ef.z);     // (e1x, e1y)
    qb.z = (unsigned)snd;
    qb.w = pk16(ef.w, 0.0f);     // (e1z, 0)
    recs[2 * addr + 0] = qa;
    recs[2 * addr + 1] = qb;
}

// One wave per node, 4 nodes/block, no barriers (wave-private LDS regions).
// Byte-equivalent to node_v17 (94.5us measured, passed).
__global__ __launch_bounds__(256) void node_v21_kernel(
    const float* __restrict__ node_feats,    // N x 32
    const float* __restrict__ w2g,           // 8 x 48
    const int* __restrict__ off,             // off[N+1]
    const uint4* __restrict__ recs,
    float* __restrict__ out,                 // N x 96
    int N)
{
    const int lane = threadIdx.x & 63;
    const int wv   = threadIdx.x >> 6;   // 0..3 = local node
    const int node = blockIdx.x * 4 + wv;

    __shared__ float nf_lds[4][CH][36];      // 9 KB (36: bank-balanced writes)
    __shared__ float scr[4][128];            // 2 KB epilogue scratch

    // ---- per-lane product-slot tables (all loop-invariant) ----
    int kA, iA, selA; float scA = 1.0f;
    if (lane < 8)       { kA = lane;         iA = lane;     selA = 0; }
    else if (lane < 16) { kA = lane;         iA = lane - 8; selA = 1; }
    else if (lane < 40) { int t = lane - 16; kA = 16 + t / 3; iA = 8 + t;
                          selA = 2 + t % 3;  scA = 0.57735026918962576f; }
    else                { int t = lane - 40; kA = 24 + t / 3; iA = 8 + t; selA = 0; }

    int kB, iB, selB; const bool deadB = (lane >= 48);
    if (lane < 24)      { int t = lane;      kB = 32 + t / 3; iB = t / 3; selB = 2 + t % 3; }
    else if (lane < 48) { int t = lane - 24; kB = 40 + t / 3; iB = 8 + t; selB = 1; }
    else                { kB = 0; iB = 0; selB = 0; }

    // one-hot f16 masks: f = fdot2(qb.x, m0) + fdot2(qb.y, m1) + fdot2(qb.w, m2)
    // qb.x=(1,e0) qb.y=(e1x,e1y) qb.w=(e1z,0); sel: 0->1, 1->e0, 2..4->e1xyz
    half2v mA0 = {0, 0}, mA1 = {0, 0}, mA2 = {0, 0};
    if      (selA == 0) mA0.x = (_Float16)1.f;
    else if (selA == 1) mA0.y = (_Float16)1.f;
    else if (selA == 2) mA1.x = (_Float16)1.f;
    else if (selA == 3) mA1.y = (_Float16)1.f;
    else                mA2.x = (_Float16)1.f;
    half2v mB0 = {0, 0}, mB1 = {0, 0}, mB2 = {0, 0};
    if (!deadB) {
        if      (selB == 1) mB0.y = (_Float16)1.f;
        else if (selB == 2) mB1.x = (_Float16)1.f;
        else if (selB == 3) mB1.y = (_Float16)1.f;
        else                mB2.x = (_Float16)1.f;
    }

    half2v wpA[4], wpB[4];
#pragma unroll
    for (int i = 0; i < 4; ++i) {
        wpA[i].x = (_Float16)(w2g[(2 * i + 0) * 48 + kA] * scA);
        wpA[i].y = (_Float16)(w2g[(2 * i + 1) * 48 + kA] * scA);
        wpB[i].x = deadB ? (_Float16)0.f : (_Float16)(w2g[(2 * i + 0) * 48 + kB]);
        wpB[i].y = deadB ? (_Float16)0.f : (_Float16)(w2g[(2 * i + 1) * 48 + kB]);
    }

    if (node >= N) return;  // safe: no __syncthreads in this kernel

    int base  = off[node];
    int count = off[node + 1] - base;
    // scalar-root: wave-uniform values into SGPRs so record reads become
    // s_load through the scalar cache (off the LDS/VALU pipes entirely)
    base  = __builtin_amdgcn_readfirstlane(base);
    count = __builtin_amdgcn_readfirstlane(count);
    const uint4* rp = recs + (size_t)base * 2;

    const int r_stage = lane >> 2;       // 0..15: which record's nf row I stage
    const int q_stage = lane & 3;        // 0..3: which quarter of the row

    float acc0 = 0.f, acc1 = 0.f;

    for (int c0i = 0; c0i < count; c0i += CH) {
        const int cc = min(CH, count - c0i);

        // ---- stage sender nf rows: 4 lanes per record ----
        // snd read from GLOBAL recs (qb.z = dword 6 of record)
        if (r_stage < cc) {
            const unsigned snd =
                reinterpret_cast<const unsigned*>(rp)[((size_t)c0i + r_stage) * 8 + 6];
            const float4* src = reinterpret_cast<const float4*>(node_feats)
                                + (size_t)snd * 8 + q_stage * 2;
            const float4 v0 = src[0];
            const float4 v1 = src[1];
            float* dst = &nf_lds[wv][r_stage][q_stage * 8];
            *reinterpret_cast<float4*>(dst)     = v0;
            *reinterpret_cast<float4*>(dst + 4) = v1;
        }

        // ---- compute: records via scalar loads, nf via LDS b32 ----
#pragma unroll 4
        for (int i = 0; i < cc; ++i) {
            const uint4 qa = rp[(size_t)(c0i + i) * 2 + 0];  // uniform -> s_load
            const uint4 qb = rp[(size_t)(c0i + i) * 2 + 1];  // uniform -> s_load

            float wAv = dot2h(qa.x, wpA[0], 0.f);
            wAv = dot2h(qa.y, wpA[1], wAv);
            wAv = dot2h(qa.z, wpA[2], wAv);
            wAv = dot2h(qa.w, wpA[3], wAv);
            float wBv = dot2h(qa.x, wpB[0], 0.f);
            wBv = dot2h(qa.y, wpB[1], wBv);
            wBv = dot2h(qa.z, wpB[2], wBv);
            wBv = dot2h(qa.w, wpB[3], wBv);

            // edge factor via one-hot fdot2 (no cvt, no selects)
            float fA = dot2h(qb.x, mA0, 0.f);
            fA = dot2h(qb.y, mA1, fA);
            fA = dot2h(qb.w, mA2, fA);
            float fB = dot2h(qb.x, mB0, 0.f);
            fB = dot2h(qb.y, mB1, fB);
            fB = dot2h(qb.w, mB2, fB);

            const float n0 = nf_lds[wv][i][iA];   // conflict-free
            const float n1 = nf_lds[wv][i][iB];   // broadcast groups

            acc0 = fmaf(wAv, n0 * fA, acc0);
            acc1 = fmaf(wBv, n1 * fB, acc1);
        }
    }

    // ---- epilogue: merge type2 triples, permute to output layout ----
    scr[wv][lane]      = acc0;
    scr[wv][64 + lane] = acc1;
    // same-wave LDS: no barrier needed, compiler inserts lgkmcnt waits
    float o0;
    if (lane < 16) {
        o0 = scr[wv][lane];
    } else if (lane < 24) {
        const int t = 16 + 3 * (lane - 16);
        o0 = scr[wv][t] + scr[wv][t + 1] + scr[wv][t + 2];
    } else {
        o0 = scr[wv][lane + 16];   // comps 24..47 <- slot0[40+..]; 48..63 <- slot1[0..15]
    }
    float* orow = out + (size_t)node * 96;
    orow[lane] = o0;
    if (lane < 32) orow[64 + lane] = scr[wv][80 + lane];  // comps 64..95 <- slot1[16..47]
}

extern "C" void kernel_launch(void* const* d_in, const int* in_sizes, int n_in,
                              void* d_out, int out_size, void* d_ws, size_t ws_size,
                              hipStream_t stream) {
    const float* node_feats    = (const float*)d_in[0];
    const float* edge_features = (const float*)d_in[1];
    const float* radial        = (const float*)d_in[2];
    const float* w1            = (const float*)d_in[3];
    const float* w2            = (const float*)d_in[4];
    const int*   senders       = (const int*)d_in[5];
    const int*   receivers     = (const int*)d_in[6];
    float* out = (float*)d_out;

    const int E = in_sizes[5];
    const int N = out_size / 96;
    const int eblocks = (E + 255) / 256;
    const int nblocks = (N + 3) / 4;      // 4 nodes/block, 1 wave/node
    const int T = (N + 2047) / 2048;      // scan tiles (25 for N=50K)

    // ws layout: recs[E*32] | cnt[N] | off[N+1] | cursor[N] | chain[T] | tilecnt
    uint4* recs  = (uint4*)d_ws;
    int* cnt     = (int*)((char*)d_ws + (size_t)E * 32);
    int* off     = cnt + N;
    int* cursor  = off + N + 1;
    int* chain   = cursor + N;
    int* tilecnt = chain + T;

    (void)hipMemsetAsync(cnt, 0, (size_t)N * sizeof(int), stream);
    hipLaunchKernelGGL(hist_kernel, dim3(eblocks), dim3(256), 0, stream,
                       receivers, cnt, chain, tilecnt, E, T);
    hipLaunchKernelGGL(scan_chain_kernel, dim3(T), dim3(256), 0, stream,
                       cnt, off, cursor, chain, tilecnt, N, E, T);
    hipLaunchKernelGGL(build_recs_kernel, dim3(eblocks), dim3(256), 0, stream,
                       edge_features, radial, w1, senders, receivers,
                       cursor, recs, E);
    hipLaunchKernelGGL(node_v21_kernel, dim3(nblocks), dim3(256), 0, stream,
                       node_feats, w2, off, recs, out, N);
}